// Round 1
// baseline (548.660 us; speedup 1.0000x reference)
//
#include <hip/hip_runtime.h>
#include <math.h>

#define EPSV 1e-5

// d_ws layout: double acc[2] = { sum(x), sum(x*x) }  (16 bytes)

__global__ void vn_init(double* __restrict__ acc) {
    acc[0] = 0.0;
    acc[1] = 0.0;
}

__global__ void vn_reduce(const float4* __restrict__ xv, const float* __restrict__ xs,
                          double* __restrict__ acc, long long nvec, long long ntail) {
    double s = 0.0, s2 = 0.0;
    long long tid = (long long)blockIdx.x * blockDim.x + threadIdx.x;
    long long stride = (long long)gridDim.x * blockDim.x;
    for (long long i = tid; i < nvec; i += stride) {
        float4 v = xv[i];
        double a = (double)v.x, b = (double)v.y, c = (double)v.z, d = (double)v.w;
        s += (a + b) + (c + d);
        s2 = fma(a, a, s2);
        s2 = fma(b, b, s2);
        s2 = fma(c, c, s2);
        s2 = fma(d, d, s2);
    }
    if (tid < ntail) {
        double a = (double)xs[nvec * 4 + tid];
        s += a;
        s2 = fma(a, a, s2);
    }
    // wave (64-lane) butterfly reduce
    #pragma unroll
    for (int off = 32; off > 0; off >>= 1) {
        s  += __shfl_down(s, off, 64);
        s2 += __shfl_down(s2, off, 64);
    }
    __shared__ double ls[8][2];
    int lane = threadIdx.x & 63;
    int wv = threadIdx.x >> 6;
    if (lane == 0) { ls[wv][0] = s; ls[wv][1] = s2; }
    __syncthreads();
    if (threadIdx.x == 0) {
        int nw = blockDim.x >> 6;
        double ts = 0.0, t2 = 0.0;
        for (int i = 0; i < nw; ++i) { ts += ls[i][0]; t2 += ls[i][1]; }
        atomicAdd(&acc[0], ts);
        atomicAdd(&acc[1], t2);
    }
}

__global__ void vn_norm(const float4* __restrict__ xv, const float* __restrict__ xs,
                        float4* __restrict__ yv, float* __restrict__ ys,
                        const double* __restrict__ acc,
                        const float* __restrict__ cntp, const float* __restrict__ meanp,
                        const float* __restrict__ m2p,
                        float* __restrict__ out_scalars,
                        long long nvec, long long ntail, double n) {
    double sum = acc[0], sumsq = acc[1];
    double count = (double)*cntp;
    double mean  = (double)*meanp;
    double m2    = (double)*m2p;

    double bmean = sum / n;
    double bm2 = sumsq - n * bmean * bmean;
    if (bm2 < 0.0) bm2 = 0.0;
    double new_count = count + n;
    double delta = bmean - mean;
    double new_mean = mean + delta * n / new_count;
    double new_m2 = m2 + bm2 + delta * delta * count * n / new_count;
    double var = new_m2 / fmax(new_count - 1.0, 1.0);
    double inv_std = 1.0 / sqrt(var + EPSV);

    float nm = (float)new_mean;
    float is = (float)inv_std;

    long long tid = (long long)blockIdx.x * blockDim.x + threadIdx.x;
    if (tid == 0) {
        out_scalars[0] = (float)new_count;
        out_scalars[1] = (float)new_mean;
        out_scalars[2] = (float)new_m2;
    }
    long long stride = (long long)gridDim.x * blockDim.x;
    for (long long i = tid; i < nvec; i += stride) {
        float4 v = xv[i];
        float4 o;
        o.x = (v.x - nm) * is;
        o.y = (v.y - nm) * is;
        o.z = (v.z - nm) * is;
        o.w = (v.w - nm) * is;
        yv[i] = o;
    }
    if (tid < ntail) {
        long long j = nvec * 4 + tid;
        ys[j] = (xs[j] - nm) * is;
    }
}

extern "C" void kernel_launch(void* const* d_in, const int* in_sizes, int n_in,
                              void* d_out, int out_size, void* d_ws, size_t ws_size,
                              hipStream_t stream) {
    const float* x     = (const float*)d_in[0];
    const float* cntp  = (const float*)d_in[1];
    const float* meanp = (const float*)d_in[2];
    const float* m2p   = (const float*)d_in[3];
    float* out = (float*)d_out;

    long long n = (long long)in_sizes[0];
    long long nvec = n >> 2;
    long long ntail = n & 3;

    double* acc = (double*)d_ws;

    const int threads = 256;
    int blocks = 4096;
    long long need = (nvec + threads - 1) / threads;
    if (need < 1) need = 1;
    if (need < blocks) blocks = (int)need;

    vn_init<<<1, 1, 0, stream>>>(acc);
    vn_reduce<<<blocks, threads, 0, stream>>>((const float4*)x, x, acc, nvec, ntail);
    vn_norm<<<blocks, threads, 0, stream>>>((const float4*)x, x,
                                            (float4*)out, out,
                                            acc, cntp, meanp, m2p,
                                            out + n, nvec, ntail, (double)n);
}

// Round 2
// 479.722 us; speedup vs baseline: 1.1437x; 1.1437x over previous
//
#include <hip/hip_runtime.h>
#include <math.h>

#define EPSV 1e-5

typedef float v4f __attribute__((ext_vector_type(4)));

// d_ws layout: double2 partials[NBLK]  (NBLK = 2048 -> 32 KB)

__global__ __launch_bounds__(256) void vn_partial(
    const float4* __restrict__ xv, const float* __restrict__ xs,
    double2* __restrict__ partials, long long nvec, long long ntail)
{
    double s = 0.0, s2 = 0.0;
    long long tid = (long long)blockIdx.x * blockDim.x + threadIdx.x;
    long long stride = (long long)gridDim.x * blockDim.x;
    for (long long i = tid; i < nvec; i += stride) {
        float4 v = xv[i];
        double a = (double)v.x, b = (double)v.y, c = (double)v.z, d = (double)v.w;
        s += (a + b) + (c + d);
        s2 = fma(a, a, s2);
        s2 = fma(b, b, s2);
        s2 = fma(c, c, s2);
        s2 = fma(d, d, s2);
    }
    if (tid < ntail) {
        double a = (double)xs[nvec * 4 + tid];
        s += a;
        s2 = fma(a, a, s2);
    }
    // wave (64-lane) reduce
    #pragma unroll
    for (int off = 32; off > 0; off >>= 1) {
        s  += __shfl_down(s, off, 64);
        s2 += __shfl_down(s2, off, 64);
    }
    __shared__ double ls[4][2];
    int lane = threadIdx.x & 63;
    int wv = threadIdx.x >> 6;
    if (lane == 0) { ls[wv][0] = s; ls[wv][1] = s2; }
    __syncthreads();
    if (threadIdx.x == 0) {
        int nw = blockDim.x >> 6;
        double ts = 0.0, t2 = 0.0;
        for (int i = 0; i < nw; ++i) { ts += ls[i][0]; t2 += ls[i][1]; }
        partials[blockIdx.x] = make_double2(ts, t2);
    }
}

__global__ __launch_bounds__(256) void vn_norm(
    const float4* __restrict__ xv, const float* __restrict__ xs,
    float4* __restrict__ yv, float* __restrict__ ys,
    const double2* __restrict__ partials, int nparts,
    const float* __restrict__ cntp, const float* __restrict__ meanp,
    const float* __restrict__ m2p,
    float* __restrict__ out_scalars,
    long long nvec, long long ntail, double n)
{
    // every block redundantly folds the partials (L2-broadcast, ~16 KB)
    double s = 0.0, s2 = 0.0;
    for (int i = threadIdx.x; i < nparts; i += blockDim.x) {
        double2 p = partials[i];
        s += p.x; s2 += p.y;
    }
    #pragma unroll
    for (int off = 32; off > 0; off >>= 1) {
        s  += __shfl_down(s, off, 64);
        s2 += __shfl_down(s2, off, 64);
    }
    __shared__ double ls[4][2];
    __shared__ float snm, sis;
    int lane = threadIdx.x & 63;
    int wv = threadIdx.x >> 6;
    if (lane == 0) { ls[wv][0] = s; ls[wv][1] = s2; }
    __syncthreads();
    if (threadIdx.x == 0) {
        int nw = blockDim.x >> 6;
        double sum = 0.0, sumsq = 0.0;
        for (int i = 0; i < nw; ++i) { sum += ls[i][0]; sumsq += ls[i][1]; }
        double count = (double)*cntp;
        double mean  = (double)*meanp;
        double m2    = (double)*m2p;
        double bmean = sum / n;
        double bm2 = sumsq - n * bmean * bmean;
        if (bm2 < 0.0) bm2 = 0.0;
        double new_count = count + n;
        double delta = bmean - mean;
        double new_mean = mean + delta * n / new_count;
        double new_m2 = m2 + bm2 + delta * delta * count * n / new_count;
        double var = new_m2 / fmax(new_count - 1.0, 1.0);
        double inv_std = 1.0 / sqrt(var + EPSV);
        snm = (float)new_mean;
        sis = (float)inv_std;
        if (blockIdx.x == 0) {
            out_scalars[0] = (float)new_count;
            out_scalars[1] = (float)new_mean;
            out_scalars[2] = (float)new_m2;
        }
    }
    __syncthreads();
    float nm = snm;
    float is = sis;

    long long tid = (long long)blockIdx.x * blockDim.x + threadIdx.x;
    long long stride = (long long)gridDim.x * blockDim.x;
    for (long long i = tid; i < nvec; i += stride) {
        float4 v = xv[i];
        v4f o;
        o.x = (v.x - nm) * is;
        o.y = (v.y - nm) * is;
        o.z = (v.z - nm) * is;
        o.w = (v.w - nm) * is;
        // nontemporal: don't let y evict x from Infinity Cache
        __builtin_nontemporal_store(o, (v4f*)&yv[i]);
    }
    if (tid < ntail) {
        long long j = nvec * 4 + tid;
        float r = (xs[j] - nm) * is;
        __builtin_nontemporal_store(r, &ys[j]);
    }
}

extern "C" void kernel_launch(void* const* d_in, const int* in_sizes, int n_in,
                              void* d_out, int out_size, void* d_ws, size_t ws_size,
                              hipStream_t stream) {
    const float* x     = (const float*)d_in[0];
    const float* cntp  = (const float*)d_in[1];
    const float* meanp = (const float*)d_in[2];
    const float* m2p   = (const float*)d_in[3];
    float* out = (float*)d_out;

    long long n = (long long)in_sizes[0];
    long long nvec = n >> 2;
    long long ntail = n & 3;

    double2* partials = (double2*)d_ws;

    const int threads = 256;
    int blocks = 2048;
    long long need = (nvec + threads - 1) / threads;
    if (need < 1) need = 1;
    if (need < blocks) blocks = (int)need;

    vn_partial<<<blocks, threads, 0, stream>>>((const float4*)x, x, partials, nvec, ntail);
    vn_norm<<<blocks, threads, 0, stream>>>((const float4*)x, x,
                                            (float4*)out, out,
                                            partials, blocks,
                                            cntp, meanp, m2p,
                                            out + n, nvec, ntail, (double)n);
}